// Round 3
// baseline (170.698 us; speedup 1.0000x reference)
//
#include <hip/hip_runtime.h>
#include <math.h>

#define BLOCK 64            // single-wave workgroups: no s_barrier/vmcnt drains
#define NF 32
#define NDOF 29
#define SLOT_F4 5           // float4 per batch slot in staging (4 data + 1 pad)

__global__ __launch_bounds__(BLOCK) void fk_kernel(
    const float* __restrict__ ja,       // (B,29)
    const float* __restrict__ axes,     // (32,3)
    const float* __restrict__ origins,  // (32,4,4)
    const float* __restrict__ mmul,     // (2,)
    const float* __restrict__ moff,     // (2,)
    const int*   __restrict__ ctrl,     // (29,)
    const int*   __restrict__ msrc,     // (2,)
    const int*   __restrict__ mdst,     // (2,)
    const int*   __restrict__ types,    // (32,)
    float*       __restrict__ out,      // (B,32,4,4)
    int B)
{
    __shared__ float s_ax[NF][3];
    __shared__ float s_or[NF][12];          // top 3 rows of each origin
    __shared__ int   s_type[NF];
    __shared__ int   s_slot[NF];
    __shared__ float s_mult[NF];
    __shared__ float s_off[NF];
    __shared__ float s_ang[NDOF][BLOCK];    // transposed angles [dof][batch]
    __shared__ float4 s_out[2][BLOCK * SLOT_F4]; // double-buffered frame staging

    const int lane = threadIdx.x;

    if (lane < NF) {
        const int f = lane;
        s_ax[f][0] = axes[f*3+0];
        s_ax[f][1] = axes[f*3+1];
        s_ax[f][2] = axes[f*3+2];
        #pragma unroll
        for (int r = 0; r < 3; ++r)
            #pragma unroll
            for (int c = 0; c < 4; ++c)
                s_or[f][r*4+c] = origins[f*16 + r*4 + c];
        s_type[f] = types[f];
        // fold ctrl scatter + mimic joints into: angle = mult * ja[slot] + off
        int slot = -1;
        for (int j = 0; j < NDOF; ++j) if (ctrl[j] == f) slot = j;
        float mu = 1.0f, of = 0.0f;
        for (int m = 0; m < 2; ++m) {
            if (mdst[m] == f) {
                const int sf = msrc[m];
                for (int j = 0; j < NDOF; ++j) if (ctrl[j] == sf) slot = j;
                mu = mmul[m]; of = moff[m];
            }
        }
        s_slot[f] = slot; s_mult[f] = mu; s_off[f] = of;
    }

    // coalesced stage of this wave's 64 batches' angles into transposed LDS
    const long blk0 = (long)blockIdx.x * BLOCK;
    {
        const long base = blk0 * NDOF;
        const long lim  = (long)B * NDOF;
        #pragma unroll 1
        for (int k = 0; k < NDOF; ++k) {
            const int  i = k * BLOCK + lane;
            const long g = base + i;
            s_ang[i % NDOF][i / NDOF] = (g < lim) ? ja[g] : 0.0f;
        }
    }
    // only barrier in the kernel: before it, zero stores are in flight
    __syncthreads();

    float Pr[9], Pt[3];   // running chain pose (3x4 affine)
    float Qr[9], Qt[3];   // saved pose of frame 10 (parents of 30,31)

    float4* const out4 = (float4*)out;
    const long lim_b = (long)B;

    #pragma unroll 1
    for (int f = 0; f < NF; ++f) {
        // ---- local motion of frame f ----
        const int   slot = s_slot[f];
        const float a = (slot >= 0) ? fmaf(s_mult[f], s_ang[slot][lane], s_off[f]) : 0.0f;
        const float wx = a * s_ax[f][0];
        const float wy = a * s_ax[f][1];
        const float wz = a * s_ax[f][2];
        const int ty = s_type[f];
        float R0,R1,R2,R3,R4,R5,R6,R7,R8;
        if (ty == 1) {
            const float t2 = wx*wx + wy*wy + wz*wz;
            const float th = sqrtf(t2 + 1e-18f);
            const float inv = 1.0f / th;
            const float kx = wx*inv, ky = wy*inv, kz = wz*inv;
            float s, c;
            __sincosf(th, &s, &c);
            const float v = 1.0f - c;
            R0 = fmaf(v*kx, kx, c);
            R1 = v*kx*ky - s*kz;
            R2 = v*kx*kz + s*ky;
            R3 = v*kx*ky + s*kz;
            R4 = fmaf(v*ky, ky, c);
            R5 = v*ky*kz - s*kx;
            R6 = v*kx*kz - s*ky;
            R7 = v*ky*kz + s*kx;
            R8 = fmaf(v*kz, kz, c);
        } else {
            R0=1.f;R1=0.f;R2=0.f;R3=0.f;R4=1.f;R5=0.f;R6=0.f;R7=0.f;R8=1.f;
        }
        float tx, tyv, tz;
        if (ty == 2) { tx = wx; tyv = wy; tz = wz; }
        else         { tx = 0.f; tyv = 0.f; tz = 0.f; }

        float Lr[9], Lt[3];
        const float* O = s_or[f];
        #pragma unroll
        for (int r = 0; r < 3; ++r) {
            const float o0 = O[r*4+0], o1 = O[r*4+1], o2 = O[r*4+2], o3 = O[r*4+3];
            Lr[r*3+0] = o0*R0 + o1*R3 + o2*R6;
            Lr[r*3+1] = o0*R1 + o1*R4 + o2*R7;
            Lr[r*3+2] = o0*R2 + o1*R5 + o2*R8;
            Lt[r]     = o0*tx + o1*tyv + o2*tz + o3;
        }

        // ---- compose with parent ----
        float Wr[9], Wt[3];
        if (f == 0) {
            #pragma unroll
            for (int i = 0; i < 9; ++i) Wr[i] = Lr[i];
            Wt[0]=Lt[0]; Wt[1]=Lt[1]; Wt[2]=Lt[2];
        } else {
            const float* PR = (f >= 30) ? Qr : Pr;   // 30,31 hang off frame 10
            const float* PT = (f >= 30) ? Qt : Pt;
            #pragma unroll
            for (int r = 0; r < 3; ++r) {
                const float p0 = PR[r*3+0], p1 = PR[r*3+1], p2 = PR[r*3+2];
                Wr[r*3+0] = p0*Lr[0] + p1*Lr[3] + p2*Lr[6];
                Wr[r*3+1] = p0*Lr[1] + p1*Lr[4] + p2*Lr[7];
                Wr[r*3+2] = p0*Lr[2] + p1*Lr[5] + p2*Lr[8];
                Wt[r]     = p0*Lt[0] + p1*Lt[1] + p2*Lt[2] + PT[r];
            }
        }
        if (f <= 29) {
            #pragma unroll
            for (int i = 0; i < 9; ++i) Pr[i] = Wr[i];
            Pt[0]=Wt[0]; Pt[1]=Wt[1]; Pt[2]=Wt[2];
            if (f == 10) {
                #pragma unroll
                for (int i = 0; i < 9; ++i) Qr[i] = Pr[i];
                Qt[0]=Pt[0]; Qt[1]=Pt[1]; Qt[2]=Pt[2];
            }
        }

        // ---- wave-private transpose + coalesced full-line stores ----
        float4* const buf = s_out[f & 1];
        {
            float4* slot4 = &buf[lane * SLOT_F4];
            slot4[0] = make_float4(Wr[0], Wr[1], Wr[2], Wt[0]);
            slot4[1] = make_float4(Wr[3], Wr[4], Wr[5], Wt[1]);
            slot4[2] = make_float4(Wr[6], Wr[7], Wr[8], Wt[2]);
            slot4[3] = make_float4(0.0f, 0.0f, 0.0f, 1.0f);
        }
        __builtin_amdgcn_wave_barrier();   // scheduling fence only; DS is in-order in-wave
        const int q  = lane & 3;
        const int b0 = lane >> 2;
        #pragma unroll
        for (int k = 0; k < 4; ++k) {
            const int  b  = b0 + 16 * k;
            const long bb = blk0 + b;
            if (bb < lim_b)
                out4[bb * 128 + f * 4 + q] = buf[b * SLOT_F4 + q];
        }
        __builtin_amdgcn_wave_barrier();
    }
}

extern "C" void kernel_launch(void* const* d_in, const int* in_sizes, int n_in,
                              void* d_out, int out_size, void* d_ws, size_t ws_size,
                              hipStream_t stream) {
    const float* ja   = (const float*)d_in[0];
    const float* axes = (const float*)d_in[1];
    const float* orig = (const float*)d_in[2];
    const float* mmul = (const float*)d_in[3];
    const float* moff = (const float*)d_in[4];
    const int*   ctrl = (const int*)d_in[5];
    const int*   msrc = (const int*)d_in[6];
    const int*   mdst = (const int*)d_in[7];
    const int*   typs = (const int*)d_in[8];
    float* out = (float*)d_out;

    const int B = in_sizes[0] / NDOF;
    const int grid = (B + BLOCK - 1) / BLOCK;
    fk_kernel<<<grid, BLOCK, 0, stream>>>(ja, axes, orig, mmul, moff,
                                          ctrl, msrc, mdst, typs, out, B);
}